// Round 11
// baseline (173.828 us; speedup 1.0000x reference)
//
#include <hip/hip_runtime.h>
#include <hip/hip_bf16.h>

typedef __hip_bfloat16 bf16;
typedef __attribute__((ext_vector_type(8))) short short8;
typedef __attribute__((ext_vector_type(4))) float float4v;

#define NN   768
#define NEPS 767

// ---- cross-kernel scratch ----
__device__ float g_emb1[NN*64];
__device__ float g_sa2[NN*32];
__device__ float g_sb2[NN*32];
__device__ float g_agg[640];     // 4 replicas x 160
__device__ int   g_cnt;

struct Ptrs { const void* p[28]; };

__device__ __forceinline__ float b2f(bf16 v){ return __bfloat162float(v); }
__device__ __forceinline__ float LD(const void* p, int i, int f32){
  return f32 ? ((const float*)p)[i] : b2f(((const bf16*)p)[i]);
}
__device__ __forceinline__ int detect_f32(const void* f){
  float v = ((const float*)f)[0];
  return (fabsf(v - 3.14159265f) < 0.01f) ? 1 : 0;
}
__device__ __forceinline__ float fast_rcp(float x){ return __builtin_amdgcn_rcpf(x); }
__device__ __forceinline__ float silu_f(float p){ return p * fast_rcp(1.f + __expf(-p)); }
__device__ __forceinline__ unsigned short rne_bf16(float x){
  unsigned int b = __float_as_uint(x);
  return (unsigned short)((b + 0x7fffu + ((b >> 16) & 1u)) >> 16);
}

// branch-hoisted strided dot: sum_j x[k0+j] * W[base + (k0+j)*stride + col]
template<int NJ>
__device__ __forceinline__ float dotn(const void* wp, int base, int stride, int col,
                                      const float* x, int k0, int isf){
  float p = 0.f;
  if (isf){
    const float* f = (const float*)wp;
    #pragma unroll
    for (int j = 0; j < NJ; j++){ int k = k0 + j; p = fmaf(x[k], f[base + k*stride + col], p); }
  } else {
    const bf16* h = (const bf16*)wp;
    #pragma unroll
    for (int j = 0; j < NJ; j++){ int k = k0 + j; p = fmaf(x[k], b2f(h[base + k*stride + col]), p); }
  }
  return p;
}

// ---------------- K1: edge layer 1 + update-1 (no precompute kernel needed) ----------------
__launch_bounds__(256)
__global__ void k_edge1(Ptrs P, const int* __restrict__ charges){
  __shared__ __align__(16) float pos[NN*3];
  __shared__ float etabL[320];
  __shared__ __align__(16) float w0F[2048];    // mp1_w0 sender+receiver halves
  __shared__ float TBL[330];                   // receiver charge-table, stride 33
  __shared__ int   chS[NN];
  __shared__ float w1L[1024];
  __shared__ float wsum[4][32], hsumL[32], msgL[32];
  __shared__ float catU[64], hU[64], e1U[64], part[256];

  int i = blockIdx.x, t = threadIdx.x;
  int w = t >> 6, lane = t & 63, q = lane >> 4, c = lane & 15;
  int isf = detect_f32(P.p[2]);

  if (i == 0){
    for (int idx = t; idx < 640; idx += 256) g_agg[idx] = 0.f;
    if (t == 0) g_cnt = 0;
  }
  for (int idx = t; idx < NN*3; idx += 256) pos[idx]   = LD(P.p[0], idx, isf);
  for (int idx = t; idx < 320;  idx += 256) etabL[idx] = LD(P.p[3], idx, isf);
  for (int idx = t; idx < 2048; idx += 256) w0F[idx]   = LD(P.p[4], idx, isf);
  for (int idx = t; idx < 1024; idx += 256) w1L[idx]   = LD(P.p[6], idx, isf);
  for (int idx = t; idx < NN;   idx += 256) chS[idx]   = charges[idx];

  // B fragments straight from raw mp1_w0 rows 64..95 (bf16: direct bit copy)
  short8 bfr0, bfr1;
  if (isf){
    const float* wp = (const float*)P.p[4];
    #pragma unroll
    for (int j = 0; j < 8; j++){
      int row = q*8 + j;
      bfr0[j] = (short)rne_bf16(wp[2048 + row*32 + c]);
      bfr1[j] = (short)rne_bf16(wp[2048 + row*32 + 16 + c]);
    }
  } else {
    const short* wp = (const short*)P.p[4];
    #pragma unroll
    for (int j = 0; j < 8; j++){
      int row = q*8 + j;
      bfr0[j] = wp[2048 + row*32 + c];
      bfr1[j] = wp[2048 + row*32 + 16 + c];
    }
  }
  float fj[8];
  #pragma unroll
  for (int j = 0; j < 8; j++) fj[j] = LD(P.p[2], q*8 + j, isf) * 0.1f;
  __syncthreads();   // etabL/w0F/pos/chS ready

  // per-block charge table (receiver half of mp1_w0); 320 > 256 -> strided
  for (int idx = t; idx < 320; idx += 256){
    int ch = idx >> 5, cc = idx & 31;
    float b = 0.f;
    #pragma unroll
    for (int k = 0; k < 32; k++) b = fmaf(etabL[ch*32 + k], w0F[1024 + k*32 + cc], b);
    TBL[ch*33 + cc] = b;
  }
  int chI = chS[i];
  // preB: own-row sender-half + bias (per-thread, 64 LDS FMAs)
  float preB0 = LD(P.p[5], c, isf), preB1 = LD(P.p[5], 16 + c, isf);
  #pragma unroll
  for (int k = 0; k < 32; k++){
    float e = etabL[chI*32 + k];
    preB0 = fmaf(e, w0F[k*32 + c],      preB0);
    preB1 = fmaf(e, w0F[k*32 + 16 + c], preB1);
  }
  __syncthreads();   // TBL ready

  float px = pos[i*3], py = pos[i*3+1], pz = pos[i*3+2];
  float xs[12], scv[12];
  #pragma unroll
  for (int s = 0; s < 12; s++){
    int el = (w + s*4)*16 + c;
    int ela = (el < NEPS) ? el : 0;
    int r = ela + (ela >= i);
    float dx = px - pos[r*3], dy = py - pos[r*3+1], dz = pz - pos[r*3+2];
    float d = sqrtf(fmaf(dx, dx, fmaf(dy, dy, dz*dz)));
    xs[s] = d + 1e-8f;
    scv[s] = 0.44721359549995793f * fast_rcp(xs[s]);
  }

  float sum0 = 0.f, sum1 = 0.f;
  #pragma unroll 4
  for (int s = 0; s < 12; s++){
    int tl = w + s*4;
    float sb0[4], sb1[4];
    #pragma unroll
    for (int p = 0; p < 4; p++){
      int el2 = tl*16 + q*4 + p;
      int e2a = (el2 < NEPS) ? el2 : 0;
      int r2 = e2a + (e2a >= i);
      int ch2 = chS[r2];
      sb0[p] = TBL[ch2*33 + c];
      sb1[p] = TBL[ch2*33 + 16 + c];
    }
    short8 af;
    #pragma unroll
    for (int j = 0; j < 8; j++) af[j] = (short)rne_bf16(scv[s] * __sinf(fj[j]*xs[s]));
    float4v z = {0.f, 0.f, 0.f, 0.f};
    float4v a0 = __builtin_amdgcn_mfma_f32_16x16x32_bf16(af, bfr0, z, 0, 0, 0);
    float4v a1 = __builtin_amdgcn_mfma_f32_16x16x32_bf16(af, bfr1, z, 0, 0, 0);
    #pragma unroll
    for (int p = 0; p < 4; p++){
      int el2 = tl*16 + q*4 + p;
      if (el2 < NEPS){
        sum0 += silu_f(a0[p] + preB0 + sb0[p]);
        sum1 += silu_f(a1[p] + preB1 + sb1[p]);
      }
    }
  }
  sum0 += __shfl_xor(sum0, 16); sum0 += __shfl_xor(sum0, 32);
  sum1 += __shfl_xor(sum1, 16); sum1 += __shfl_xor(sum1, 32);
  if (lane < 16){ wsum[w][lane] = sum0; wsum[w][16 + lane] = sum1; }
  __syncthreads();
  if (t < 32) hsumL[t] = wsum[0][t] + wsum[1][t] + wsum[2][t] + wsum[3][t];
  __syncthreads();
  if (t < 32){
    float y = 0.f;
    #pragma unroll
    for (int m = 0; m < 32; m++) y = fmaf(hsumL[m], w1L[m*32 + t], y);
    msgL[t] = y * (1.f/767.f) + LD(P.p[7], t, isf);
  }
  if (t < 32){ catU[t] = etabL[chI*32 + t]; catU[32 + t] = msgL[t]; }
  __syncthreads();

  // update MLP 1 (weights direct from raw global, branch-hoisted)
  int g = t >> 6, col = t & 63;
  part[t] = dotn<16>(P.p[8], 0, 64, col, catU, g*16, isf);
  __syncthreads();
  if (t < 64) hU[t] = silu_f(LD(P.p[9], t, isf) + part[t] + part[64+t] + part[128+t] + part[192+t]);
  __syncthreads();
  part[t] = dotn<16>(P.p[10], 0, 64, col, hU, g*16, isf);
  __syncthreads();
  if (t < 64){
    float y = LD(P.p[11], t, isf) + part[t] + part[64+t] + part[128+t] + part[192+t];
    e1U[t] = y;
    g_emb1[i*64 + t] = y;
  }
  __syncthreads();
  {
    int half = t >> 7, g2 = (t >> 5) & 3, c32 = t & 31;
    part[t] = dotn<16>(P.p[12], half*2048, 32, c32, e1U, g2*16, isf);
  }
  __syncthreads();
  if (t < 64){
    int half2 = t >> 5, cc = t & 31;
    float s = part[half2*128 + cc] + part[half2*128 + 32 + cc]
            + part[half2*128 + 64 + cc] + part[half2*128 + 96 + cc];
    if (half2 == 0) g_sa2[i*32 + cc] = s;
    else            g_sb2[i*32 + cc] = s;
  }
}

// ---------------- K2: edge layer 2 + update-2 + node_out + global ----------------
__launch_bounds__(256)
__global__ void k_edge2(Ptrs P, const int* __restrict__ charges, void* __restrict__ out){
  __shared__ __align__(16) float pos[NN*3];
  __shared__ float w1L[1024];
  __shared__ float noL[522];
  __shared__ float wsum[4][32], hsumL[32], msgL[32];
  __shared__ float catU[96], hU[64], aggL[160], h3L[3], part[256];
  __shared__ int lastL;

  int i = blockIdx.x, t = threadIdx.x;
  int w = t >> 6, lane = t & 63, q = lane >> 4, c = lane & 15;
  int isf = detect_f32(P.p[2]);

  for (int idx = t; idx < NN*3; idx += 256) pos[idx] = LD(P.p[0], idx, isf);
  for (int idx = t; idx < 1024; idx += 256) w1L[idx] = LD(P.p[14], idx, isf);
  for (int idx = t; idx < 522; idx += 256){
    float v;
    if      (idx < 480) v = LD(P.p[20], idx, isf);
    else if (idx < 483) v = LD(P.p[21], idx - 480, isf);
    else if (idx < 492) v = LD(P.p[22], idx - 483, isf);
    else                v = LD(P.p[23], idx - 492, isf);
    noL[idx] = v;
  }
  short8 cfr0, cfr1;
  if (isf){
    const float* wp = (const float*)P.p[12];
    #pragma unroll
    for (int j = 0; j < 8; j++){
      int row = q*8 + j;
      cfr0[j] = (short)rne_bf16(wp[4096 + row*32 + c]);
      cfr1[j] = (short)rne_bf16(wp[4096 + row*32 + 16 + c]);
    }
  } else {
    const short* wp = (const short*)P.p[12];
    #pragma unroll
    for (int j = 0; j < 8; j++){
      int row = q*8 + j;
      cfr0[j] = wp[4096 + row*32 + c];
      cfr1[j] = wp[4096 + row*32 + 16 + c];
    }
  }
  float fj[8];
  #pragma unroll
  for (int j = 0; j < 8; j++) fj[j] = LD(P.p[2], q*8 + j, isf) * 0.1f;
  float preC0 = g_sa2[i*32 + c]      + LD(P.p[13], c, isf);
  float preC1 = g_sa2[i*32 + 16 + c] + LD(P.p[13], 16 + c, isf);
  __syncthreads();

  float px = pos[i*3], py = pos[i*3+1], pz = pos[i*3+2];
  float xs[12], scv[12];
  #pragma unroll
  for (int s = 0; s < 12; s++){
    int el = (w + s*4)*16 + c;
    int ela = (el < NEPS) ? el : 0;
    int r = ela + (ela >= i);
    float dx = px - pos[r*3], dy = py - pos[r*3+1], dz = pz - pos[r*3+2];
    float d = sqrtf(fmaf(dx, dx, fmaf(dy, dy, dz*dz)));
    xs[s] = d + 1e-8f;
    scv[s] = 0.44721359549995793f * fast_rcp(xs[s]);
  }

  float sum0 = 0.f, sum1 = 0.f;
  #pragma unroll 4
  for (int s = 0; s < 12; s++){
    int tl = w + s*4;
    // SB gather issued first; the sin chain below covers its latency
    float sb0[4], sb1[4];
    #pragma unroll
    for (int p = 0; p < 4; p++){
      int el2 = tl*16 + q*4 + p;
      int e2a = (el2 < NEPS) ? el2 : 0;
      int r2 = e2a + (e2a >= i);
      sb0[p] = g_sb2[r2*32 + c];
      sb1[p] = g_sb2[r2*32 + 16 + c];
    }
    short8 af;
    #pragma unroll
    for (int j = 0; j < 8; j++) af[j] = (short)rne_bf16(scv[s] * __sinf(fj[j]*xs[s]));
    float4v z = {0.f, 0.f, 0.f, 0.f};
    float4v a0 = __builtin_amdgcn_mfma_f32_16x16x32_bf16(af, cfr0, z, 0, 0, 0);
    float4v a1 = __builtin_amdgcn_mfma_f32_16x16x32_bf16(af, cfr1, z, 0, 0, 0);
    #pragma unroll
    for (int p = 0; p < 4; p++){
      int el2 = tl*16 + q*4 + p;
      if (el2 < NEPS){
        sum0 += silu_f(a0[p] + preC0 + sb0[p]);
        sum1 += silu_f(a1[p] + preC1 + sb1[p]);
      }
    }
  }
  sum0 += __shfl_xor(sum0, 16); sum0 += __shfl_xor(sum0, 32);
  sum1 += __shfl_xor(sum1, 16); sum1 += __shfl_xor(sum1, 32);
  if (lane < 16){ wsum[w][lane] = sum0; wsum[w][16 + lane] = sum1; }
  __syncthreads();
  if (t < 32) hsumL[t] = wsum[0][t] + wsum[1][t] + wsum[2][t] + wsum[3][t];
  __syncthreads();
  if (t < 32){
    float y = 0.f;
    #pragma unroll
    for (int m = 0; m < 32; m++) y = fmaf(hsumL[m], w1L[m*32 + t], y);
    msgL[t] = y * (1.f/767.f) + LD(P.p[15], t, isf);
  }
  int chI = charges[i];
  if (t < 64) catU[t] = g_emb1[i*64 + t];
  if (t < 32){ catU[64 + t] = msgL[t]; aggL[t] = LD(P.p[3], chI*32 + t, isf); }
  __syncthreads();

  int g = t >> 6, col = t & 63;
  part[t] = dotn<24>(P.p[16], 0, 64, col, catU, g*24, isf);
  __syncthreads();
  if (t < 64) hU[t] = silu_f(LD(P.p[17], t, isf) + part[t] + part[64+t] + part[128+t] + part[192+t]);
  __syncthreads();
  part[t] = dotn<16>(P.p[18], 0, 64, col, hU, g*16, isf);
  __syncthreads();
  if (t < 64){
    float y = LD(P.p[19], t, isf) + part[t] + part[64+t] + part[128+t] + part[192+t];
    float e2 = catU[t] + y;
    aggL[32 + t] = catU[t];
    aggL[96 + t] = e2;
  }
  __syncthreads();
  if (t < 48){
    int chunk = t / 3, c3 = t - chunk*3;
    float p = 0.f;
    #pragma unroll
    for (int j = 0; j < 10; j++){ int k = chunk*10 + j; p = fmaf(aggL[k], noL[k*3 + c3], p); }
    part[t] = p;
  }
  __syncthreads();
  if (t < 3){
    float p = noL[480 + t];
    #pragma unroll
    for (int ch = 0; ch < 16; ch++) p += part[ch*3 + t];
    h3L[t] = silu_f(p);
  }
  __syncthreads();
  if (t < 3){
    float o = 0.f;
    #pragma unroll
    for (int m = 0; m < 3; m++) o = fmaf(h3L[m], noL[483 + m*3 + t], o);
    o += noL[492 + chI*3 + t];
    if (isf) ((float*)out)[i*3 + t] = o;
    else     ((bf16*)out)[i*3 + t] = __float2bfloat16(o);
  }
  // global aggregation (no fence: __syncthreads drains vmcnt -> atomics performed)
  if (t < 160) atomicAdd(&g_agg[(i & 3)*160 + t], aggL[t]);
  __syncthreads();
  if (t == 0) lastL = (atomicAdd(&g_cnt, 1) == NN - 1) ? 1 : 0;
  __syncthreads();
  if (lastL){
    float v = 0.f;
    if (t < 160){
      float s = atomicAdd(&g_agg[t], 0.f) + atomicAdd(&g_agg[160 + t], 0.f)
              + atomicAdd(&g_agg[320 + t], 0.f) + atomicAdd(&g_agg[480 + t], 0.f);
      v = s * (1.f/768.f) * LD(P.p[24], t, isf);
    }
    part[t] = v;
    __syncthreads();
    if (t == 0){
      float tot = 0.f;
      for (int k = 0; k < 160; k++) tot += part[k];
      float h = silu_f(tot + LD(P.p[25], 0, isf));
      float go = h * LD(P.p[26], 0, isf) + LD(P.p[27], 0, isf);
      if (isf) ((float*)out)[2304] = go;
      else     ((bf16*)out)[2304] = __float2bfloat16(go);
    }
  }
}

extern "C" void kernel_launch(void* const* d_in, const int* in_sizes, int n_in,
                              void* d_out, int out_size, void* d_ws, size_t ws_size,
                              hipStream_t stream) {
  Ptrs P;
  for (int k = 0; k < 28; k++) P.p[k] = d_in[k];
  const int* charges = (const int*)d_in[1];

  k_edge1<<<NN, 256, 0, stream>>>(P, charges);
  k_edge2<<<NN, 256, 0, stream>>>(P, charges, d_out);
}

// Round 12
// 165.499 us; speedup vs baseline: 1.0503x; 1.0503x over previous
//
#include <hip/hip_runtime.h>
#include <hip/hip_bf16.h>

typedef __hip_bfloat16 bf16;
typedef __attribute__((ext_vector_type(8))) short short8;
typedef __attribute__((ext_vector_type(4))) float float4v;

#define NN   768
#define NEPS 767

// ---- cross-kernel scratch ----
__device__ float g_emb1[NN*64];
__device__ float g_sa2[NN*32];
__device__ float g_sb2[NN*32];
__device__ float g_agg[640];     // 4 replicas x 160
__device__ int   g_cnt;
__device__ short8 g_rbf[NN*48*64];   // RBF A-fragments [node][tile][lane]

struct Ptrs { const void* p[28]; };

__device__ __forceinline__ float b2f(bf16 v){ return __bfloat162float(v); }
__device__ __forceinline__ float LD(const void* p, int i, int f32){
  return f32 ? ((const float*)p)[i] : b2f(((const bf16*)p)[i]);
}
__device__ __forceinline__ int detect_f32(const void* f){
  float v = ((const float*)f)[0];
  return (fabsf(v - 3.14159265f) < 0.01f) ? 1 : 0;
}
__device__ __forceinline__ float fast_rcp(float x){ return __builtin_amdgcn_rcpf(x); }
__device__ __forceinline__ float silu_f(float p){ return p * fast_rcp(1.f + __expf(-p)); }
__device__ __forceinline__ unsigned short rne_bf16(float x){
  unsigned int b = __float_as_uint(x);
  return (unsigned short)((b + 0x7fffu + ((b >> 16) & 1u)) >> 16);
}

// branch-hoisted strided dot: sum_j x[k0+j] * W[base + (k0+j)*stride + col]
template<int NJ>
__device__ __forceinline__ float dotn(const void* wp, int base, int stride, int col,
                                      const float* x, int k0, int isf){
  float p = 0.f;
  if (isf){
    const float* f = (const float*)wp;
    #pragma unroll
    for (int j = 0; j < NJ; j++){ int k = k0 + j; p = fmaf(x[k], f[base + k*stride + col], p); }
  } else {
    const bf16* h = (const bf16*)wp;
    #pragma unroll
    for (int j = 0; j < NJ; j++){ int k = k0 + j; p = fmaf(x[k], b2f(h[base + k*stride + col]), p); }
  }
  return p;
}

// ---------------- K1: edge layer 1 + update-1 + RBF store ----------------
__launch_bounds__(256)
__global__ void k_edge1(Ptrs P, const int* __restrict__ charges){
  __shared__ __align__(16) float pos[NN*3];
  __shared__ float etabL[320];
  __shared__ __align__(16) float w0F[2048];    // mp1_w0 sender+receiver halves
  __shared__ float TBL[330];                   // receiver charge-table, stride 33
  __shared__ int   chS[NN];
  __shared__ float w1L[1024];
  __shared__ float wsum[4][32], hsumL[32], msgL[32];
  __shared__ float catU[64], hU[64], e1U[64], part[256];

  int i = blockIdx.x, t = threadIdx.x;
  int w = t >> 6, lane = t & 63, q = lane >> 4, c = lane & 15;
  int isf = detect_f32(P.p[2]);

  if (i == 0){
    for (int idx = t; idx < 640; idx += 256) g_agg[idx] = 0.f;
    if (t == 0) g_cnt = 0;
  }
  for (int idx = t; idx < NN*3; idx += 256) pos[idx]   = LD(P.p[0], idx, isf);
  for (int idx = t; idx < 320;  idx += 256) etabL[idx] = LD(P.p[3], idx, isf);
  for (int idx = t; idx < 2048; idx += 256) w0F[idx]   = LD(P.p[4], idx, isf);
  for (int idx = t; idx < 1024; idx += 256) w1L[idx]   = LD(P.p[6], idx, isf);
  for (int idx = t; idx < NN;   idx += 256) chS[idx]   = charges[idx];

  // B fragments from raw mp1_w0 rows 64..95 (bf16 input: direct bit copy)
  short8 bfr0, bfr1;
  if (isf){
    const float* wp = (const float*)P.p[4];
    #pragma unroll
    for (int j = 0; j < 8; j++){
      int row = q*8 + j;
      bfr0[j] = (short)rne_bf16(wp[2048 + row*32 + c]);
      bfr1[j] = (short)rne_bf16(wp[2048 + row*32 + 16 + c]);
    }
  } else {
    const short* wp = (const short*)P.p[4];
    #pragma unroll
    for (int j = 0; j < 8; j++){
      int row = q*8 + j;
      bfr0[j] = wp[2048 + row*32 + c];
      bfr1[j] = wp[2048 + row*32 + 16 + c];
    }
  }
  float fj[8];
  #pragma unroll
  for (int j = 0; j < 8; j++) fj[j] = LD(P.p[2], q*8 + j, isf) * 0.1f;
  __syncthreads();   // etabL/w0F/pos/chS ready

  // per-block charge table (receiver half); 320 > 256 -> strided
  for (int idx = t; idx < 320; idx += 256){
    int ch = idx >> 5, cc = idx & 31;
    float b = 0.f;
    #pragma unroll
    for (int k = 0; k < 32; k++) b = fmaf(etabL[ch*32 + k], w0F[1024 + k*32 + cc], b);
    TBL[ch*33 + cc] = b;
  }
  int chI = chS[i];
  float preB0 = LD(P.p[5], c, isf), preB1 = LD(P.p[5], 16 + c, isf);
  #pragma unroll
  for (int k = 0; k < 32; k++){
    float e = etabL[chI*32 + k];
    preB0 = fmaf(e, w0F[k*32 + c],      preB0);
    preB1 = fmaf(e, w0F[k*32 + 16 + c], preB1);
  }
  __syncthreads();   // TBL ready

  float px = pos[i*3], py = pos[i*3+1], pz = pos[i*3+2];
  float xs[12], scv[12];
  #pragma unroll
  for (int s = 0; s < 12; s++){
    int el = (w + s*4)*16 + c;
    int ela = (el < NEPS) ? el : 0;
    int r = ela + (ela >= i);
    float dx = px - pos[r*3], dy = py - pos[r*3+1], dz = pz - pos[r*3+2];
    float d = sqrtf(fmaf(dx, dx, fmaf(dy, dy, dz*dz)));
    xs[s] = d + 1e-8f;
    scv[s] = 0.44721359549995793f * fast_rcp(xs[s]);
  }

  float sum0 = 0.f, sum1 = 0.f;
  #pragma unroll 4
  for (int s = 0; s < 12; s++){
    int tl = w + s*4;
    float sb0[4], sb1[4];
    #pragma unroll
    for (int p = 0; p < 4; p++){
      int el2 = tl*16 + q*4 + p;
      int e2a = (el2 < NEPS) ? el2 : 0;
      int r2 = e2a + (e2a >= i);
      int ch2 = chS[r2];
      sb0[p] = TBL[ch2*33 + c];
      sb1[p] = TBL[ch2*33 + 16 + c];
    }
    short8 af;
    #pragma unroll
    for (int j = 0; j < 8; j++) af[j] = (short)rne_bf16(scv[s] * __sinf(fj[j]*xs[s]));
    g_rbf[(i*48 + tl)*64 + lane] = af;   // coalesced dwordx4; reused by k_edge2
    float4v z = {0.f, 0.f, 0.f, 0.f};
    float4v a0 = __builtin_amdgcn_mfma_f32_16x16x32_bf16(af, bfr0, z, 0, 0, 0);
    float4v a1 = __builtin_amdgcn_mfma_f32_16x16x32_bf16(af, bfr1, z, 0, 0, 0);
    #pragma unroll
    for (int p = 0; p < 4; p++){
      int el2 = tl*16 + q*4 + p;
      if (el2 < NEPS){
        sum0 += silu_f(a0[p] + preB0 + sb0[p]);
        sum1 += silu_f(a1[p] + preB1 + sb1[p]);
      }
    }
  }
  sum0 += __shfl_xor(sum0, 16); sum0 += __shfl_xor(sum0, 32);
  sum1 += __shfl_xor(sum1, 16); sum1 += __shfl_xor(sum1, 32);
  if (lane < 16){ wsum[w][lane] = sum0; wsum[w][16 + lane] = sum1; }
  __syncthreads();
  if (t < 32) hsumL[t] = wsum[0][t] + wsum[1][t] + wsum[2][t] + wsum[3][t];
  __syncthreads();
  if (t < 32){
    float y = 0.f;
    #pragma unroll
    for (int m = 0; m < 32; m++) y = fmaf(hsumL[m], w1L[m*32 + t], y);
    msgL[t] = y * (1.f/767.f) + LD(P.p[7], t, isf);
  }
  if (t < 32){ catU[t] = etabL[chI*32 + t]; catU[32 + t] = msgL[t]; }
  __syncthreads();

  int g = t >> 6, col = t & 63;
  part[t] = dotn<16>(P.p[8], 0, 64, col, catU, g*16, isf);
  __syncthreads();
  if (t < 64) hU[t] = silu_f(LD(P.p[9], t, isf) + part[t] + part[64+t] + part[128+t] + part[192+t]);
  __syncthreads();
  part[t] = dotn<16>(P.p[10], 0, 64, col, hU, g*16, isf);
  __syncthreads();
  if (t < 64){
    float y = LD(P.p[11], t, isf) + part[t] + part[64+t] + part[128+t] + part[192+t];
    e1U[t] = y;
    g_emb1[i*64 + t] = y;
  }
  __syncthreads();
  {
    int half = t >> 7, g2 = (t >> 5) & 3, c32 = t & 31;
    part[t] = dotn<16>(P.p[12], half*2048, 32, c32, e1U, g2*16, isf);
  }
  __syncthreads();
  if (t < 64){
    int half2 = t >> 5, cc = t & 31;
    float s = part[half2*128 + cc] + part[half2*128 + 32 + cc]
            + part[half2*128 + 64 + cc] + part[half2*128 + 96 + cc];
    if (half2 == 0) g_sa2[i*32 + cc] = s;
    else            g_sb2[i*32 + cc] = s;
  }
}

// ---------------- K2: edge layer 2 (loads g_rbf) + update-2 + outputs ----------------
__launch_bounds__(256)
__global__ void k_edge2(Ptrs P, const int* __restrict__ charges, void* __restrict__ out){
  __shared__ float w1L[1024];
  __shared__ float noL[522];
  __shared__ float wsum[4][32], hsumL[32], msgL[32];
  __shared__ float catU[96], hU[64], aggL[160], h3L[3], part[256];
  __shared__ int lastL;

  int i = blockIdx.x, t = threadIdx.x;
  int w = t >> 6, lane = t & 63, q = lane >> 4, c = lane & 15;
  int isf = detect_f32(P.p[2]);

  for (int idx = t; idx < 1024; idx += 256) w1L[idx] = LD(P.p[14], idx, isf);
  for (int idx = t; idx < 522; idx += 256){
    float v;
    if      (idx < 480) v = LD(P.p[20], idx, isf);
    else if (idx < 483) v = LD(P.p[21], idx - 480, isf);
    else if (idx < 492) v = LD(P.p[22], idx - 483, isf);
    else                v = LD(P.p[23], idx - 492, isf);
    noL[idx] = v;
  }
  short8 cfr0, cfr1;
  if (isf){
    const float* wp = (const float*)P.p[12];
    #pragma unroll
    for (int j = 0; j < 8; j++){
      int row = q*8 + j;
      cfr0[j] = (short)rne_bf16(wp[4096 + row*32 + c]);
      cfr1[j] = (short)rne_bf16(wp[4096 + row*32 + 16 + c]);
    }
  } else {
    const short* wp = (const short*)P.p[12];
    #pragma unroll
    for (int j = 0; j < 8; j++){
      int row = q*8 + j;
      cfr0[j] = wp[4096 + row*32 + c];
      cfr1[j] = wp[4096 + row*32 + 16 + c];
    }
  }
  float preC0 = g_sa2[i*32 + c]      + LD(P.p[13], c, isf);
  float preC1 = g_sa2[i*32 + 16 + c] + LD(P.p[13], 16 + c, isf);

  // double-buffered pipeline over 12 tiles: load s+1 while consuming s
  float sum0 = 0.f, sum1 = 0.f;
  short8 afA = g_rbf[(i*48 + w)*64 + lane];
  float sbA0[4], sbA1[4];
  #pragma unroll
  for (int p = 0; p < 4; p++){
    int el2 = w*16 + q*4 + p;
    int e2a = (el2 < NEPS) ? el2 : 0;
    int r2 = e2a + (e2a >= i);
    sbA0[p] = g_sb2[r2*32 + c];
    sbA1[p] = g_sb2[r2*32 + 16 + c];
  }
  #pragma unroll
  for (int s = 0; s < 12; s++){
    int tl = w + s*4;
    short8 afB;
    float sbB0[4], sbB1[4];
    if (s < 11){
      int tn = tl + 4;
      afB = g_rbf[(i*48 + tn)*64 + lane];
      #pragma unroll
      for (int p = 0; p < 4; p++){
        int el2 = tn*16 + q*4 + p;
        int e2a = (el2 < NEPS) ? el2 : 0;
        int r2 = e2a + (e2a >= i);
        sbB0[p] = g_sb2[r2*32 + c];
        sbB1[p] = g_sb2[r2*32 + 16 + c];
      }
    }
    float4v z = {0.f, 0.f, 0.f, 0.f};
    float4v a0 = __builtin_amdgcn_mfma_f32_16x16x32_bf16(afA, cfr0, z, 0, 0, 0);
    float4v a1 = __builtin_amdgcn_mfma_f32_16x16x32_bf16(afA, cfr1, z, 0, 0, 0);
    #pragma unroll
    for (int p = 0; p < 4; p++){
      int el2 = tl*16 + q*4 + p;
      if (el2 < NEPS){
        sum0 += silu_f(a0[p] + preC0 + sbA0[p]);
        sum1 += silu_f(a1[p] + preC1 + sbA1[p]);
      }
    }
    if (s < 11){
      afA = afB;
      #pragma unroll
      for (int p = 0; p < 4; p++){ sbA0[p] = sbB0[p]; sbA1[p] = sbB1[p]; }
    }
  }
  sum0 += __shfl_xor(sum0, 16); sum0 += __shfl_xor(sum0, 32);
  sum1 += __shfl_xor(sum1, 16); sum1 += __shfl_xor(sum1, 32);
  if (lane < 16){ wsum[w][lane] = sum0; wsum[w][16 + lane] = sum1; }
  __syncthreads();
  if (t < 32) hsumL[t] = wsum[0][t] + wsum[1][t] + wsum[2][t] + wsum[3][t];
  __syncthreads();
  if (t < 32){
    float y = 0.f;
    #pragma unroll
    for (int m = 0; m < 32; m++) y = fmaf(hsumL[m], w1L[m*32 + t], y);
    msgL[t] = y * (1.f/767.f) + LD(P.p[15], t, isf);
  }
  int chI = charges[i];
  if (t < 64) catU[t] = g_emb1[i*64 + t];
  if (t < 32){ catU[64 + t] = msgL[t]; aggL[t] = LD(P.p[3], chI*32 + t, isf); }
  __syncthreads();

  int g = t >> 6, col = t & 63;
  part[t] = dotn<24>(P.p[16], 0, 64, col, catU, g*24, isf);
  __syncthreads();
  if (t < 64) hU[t] = silu_f(LD(P.p[17], t, isf) + part[t] + part[64+t] + part[128+t] + part[192+t]);
  __syncthreads();
  part[t] = dotn<16>(P.p[18], 0, 64, col, hU, g*16, isf);
  __syncthreads();
  if (t < 64){
    float y = LD(P.p[19], t, isf) + part[t] + part[64+t] + part[128+t] + part[192+t];
    float e2 = catU[t] + y;
    aggL[32 + t] = catU[t];
    aggL[96 + t] = e2;
  }
  __syncthreads();
  if (t < 48){
    int chunk = t / 3, c3 = t - chunk*3;
    float p = 0.f;
    #pragma unroll
    for (int j = 0; j < 10; j++){ int k = chunk*10 + j; p = fmaf(aggL[k], noL[k*3 + c3], p); }
    part[t] = p;
  }
  __syncthreads();
  if (t < 3){
    float p = noL[480 + t];
    #pragma unroll
    for (int ch = 0; ch < 16; ch++) p += part[ch*3 + t];
    h3L[t] = silu_f(p);
  }
  __syncthreads();
  if (t < 3){
    float o = 0.f;
    #pragma unroll
    for (int m = 0; m < 3; m++) o = fmaf(h3L[m], noL[483 + m*3 + t], o);
    o += noL[492 + chI*3 + t];
    if (isf) ((float*)out)[i*3 + t] = o;
    else     ((bf16*)out)[i*3 + t] = __float2bfloat16(o);
  }
  // global aggregation (no fence: __syncthreads drains vmcnt -> atomics performed)
  if (t < 160) atomicAdd(&g_agg[(i & 3)*160 + t], aggL[t]);
  __syncthreads();
  if (t == 0) lastL = (atomicAdd(&g_cnt, 1) == NN - 1) ? 1 : 0;
  __syncthreads();
  if (lastL){
    float v = 0.f;
    if (t < 160){
      float s = atomicAdd(&g_agg[t], 0.f) + atomicAdd(&g_agg[160 + t], 0.f)
              + atomicAdd(&g_agg[320 + t], 0.f) + atomicAdd(&g_agg[480 + t], 0.f);
      v = s * (1.f/768.f) * LD(P.p[24], t, isf);
    }
    part[t] = v;
    __syncthreads();
    if (t == 0){
      float tot = 0.f;
      for (int k = 0; k < 160; k++) tot += part[k];
      float h = silu_f(tot + LD(P.p[25], 0, isf));
      float go = h * LD(P.p[26], 0, isf) + LD(P.p[27], 0, isf);
      if (isf) ((float*)out)[2304] = go;
      else     ((bf16*)out)[2304] = __float2bfloat16(go);
    }
  }
}

extern "C" void kernel_launch(void* const* d_in, const int* in_sizes, int n_in,
                              void* d_out, int out_size, void* d_ws, size_t ws_size,
                              hipStream_t stream) {
  Ptrs P;
  for (int k = 0; k < 28; k++) P.p[k] = d_in[k];
  const int* charges = (const int*)d_in[1];

  k_edge1<<<NN, 256, 0, stream>>>(P, charges);
  k_edge2<<<NN, 256, 0, stream>>>(P, charges, d_out);
}